// Round 15
// baseline (265.545 us; speedup 1.0000x reference)
//
#include <hip/hip_runtime.h>

// DTTreeGRU: L=1024, B=64, D=256, H=256, K=4 (tree arity)
// Heap tree: internal nodes 0..255, leaves 256..1023 (children 4n+1..4n+4).
// Internal levels (bottom-up): starts {0,1,5,21,85}, counts {1,4,16,64,171}.
// Leaves: lh=rh=0 -> h = sigmoid(x@Wz^T+bz) * tanh(x@Wc^T+bc): one GEMM over
// interleaved Wl (512 x 256; 16-col z/c groups so z,c pair within one wave).
//
// r15 = r14 internals (proven best) + leaf v2 (A-stationary): r14 profile
// showed leaf at 63us, A-traffic-bound (each 128-row fp32 X tile re-read by
// 4 tn-blocks = ~200MB). v2: one block per row-tile holds A-fragments in
// registers for the whole K=256 and loops over all 4 tn column-tiles; only
// B staged in LDS (36.9KB dbuf). A read once (50MB).

#define L_TOT 1024

typedef __attribute__((ext_vector_type(8))) short short8;
typedef __attribute__((ext_vector_type(4))) short short4v;
typedef __attribute__((ext_vector_type(4))) float f32x4;

static __device__ __forceinline__ float bf2f(unsigned short u) {
  unsigned int x = ((unsigned int)u) << 16;
  return __builtin_bit_cast(float, x);
}
static __device__ __forceinline__ unsigned short f2bf(float f) {
  unsigned int u = __builtin_bit_cast(unsigned int, f);
  u += 0x7fffu + ((u >> 16) & 1u);
  return (unsigned short)(u >> 16);
}
static __device__ __forceinline__ float sigmf(float x) { return 1.0f / (1.0f + __expf(-x)); }
static __device__ __forceinline__ float tanhf_(float x) { return 2.0f / (1.0f + __expf(-2.0f * x)) - 1.0f; }

// lgkm-only barrier: LDS ops visible, global loads stay in flight
static __device__ __forceinline__ void bar_lgkm() {
  asm volatile("s_waitcnt lgkmcnt(0)" ::: "memory");
  __builtin_amdgcn_s_barrier();
  __builtin_amdgcn_sched_barrier(0);
}

// bijective XCD swizzle (m204): contiguous logical range per XCD
static __device__ __forceinline__ int swz_t(int orig, int nwg) {
  int q = nwg >> 3, r = nwg & 7, x = orig & 7, s = orig >> 3;
  return (x < r ? x * (q + 1) : r * (q + 1) + (x - r) * q) + s;
}

// ---- prologue: convert INTERNAL x rows -> bf16, build weights, zero pad ----
__global__ __launch_bounds__(256) void k_pre(
    const float* __restrict__ in,
    const float* __restrict__ Wgih, const float* __restrict__ Wglh, const float* __restrict__ Wgrh,
    const float* __restrict__ Wcih, const float* __restrict__ Wclh, const float* __restrict__ Wcrh,
    unsigned short* __restrict__ xb, unsigned short* __restrict__ Wg,
    unsigned short* __restrict__ Wc, unsigned short* __restrict__ Wl,
    unsigned short* __restrict__ hb) {
  int t = blockIdx.x * 256 + threadIdx.x;
  if (t < 524288) {
    const float* s = in + (size_t)t * 8;
    short8 v;
#pragma unroll
    for (int j = 0; j < 8; ++j) v[j] = (short)f2bf(s[j]);
    *(short8*)(xb + (size_t)t * 8) = v;
  }
  const int NG = 1280 * 768;
  const int NC = 256 * 768;
  const int NL = 512 * 256;
  if (t < NG) {
    int g = t / 768, k = t % 768;
    float v = (k < 256) ? Wgih[g * 256 + k] : ((k < 512) ? Wglh[g * 256 + k - 256] : Wgrh[g * 256 + k - 512]);
    Wg[t] = f2bf(v);
  } else if (t < NG + NC) {
    int t2 = t - NG;
    int g = t2 / 768, k = t2 % 768;
    float v = (k < 256) ? Wcih[g * 256 + k] : ((k < 512) ? Wclh[g * 256 + k - 256] : Wcrh[g * 256 + k - 512]);
    Wc[t2] = f2bf(v);
  } else if (t < NG + NC + NL) {
    int t2 = t - NG - NC;
    int n = t2 >> 8, k = t2 & 255;
    int g = n >> 4;
    int hc = (g >> 1) * 16 + (n & 15);
    float v = (g & 1) ? Wcih[hc * 256 + k] : Wgih[(1024 + hc) * 256 + k];
    Wl[t2] = f2bf(v);
  }
  if (t < 16384) hb[(size_t)1024 * 16384 + t] = 0;  // zero slot (node 255's 4th child)
}

// ---- per-level: lh = h[c0]+h[c1], rh = h[c2]+h[c3]; 8 elems/thread ----
__global__ __launch_bounds__(256) void k_prep(const unsigned short* __restrict__ hb,
                                              unsigned short* __restrict__ lh,
                                              unsigned short* __restrict__ rh,
                                              int rows, int row_off, int lvl_start) {
  int t = blockIdx.x * 256 + threadIdx.x;
  if (t >= rows * 32) return;
  int r = t >> 5, k8 = (t & 31) << 3;
  int gr = row_off + r;
  int node = lvl_start + (gr >> 6);
  int b = gr & 63;
  int cb = 4 * node + 1;
  int c0 = cb, c1 = cb + 1, c2 = cb + 2, c3 = cb + 3;
  c0 = (c0 < L_TOT) ? c0 : L_TOT;
  c1 = (c1 < L_TOT) ? c1 : L_TOT;
  c2 = (c2 < L_TOT) ? c2 : L_TOT;
  c3 = (c3 < L_TOT) ? c3 : L_TOT;
  const short8 v0 = *(const short8*)(hb + (size_t)c0 * 16384 + b * 256 + k8);
  const short8 v1 = *(const short8*)(hb + (size_t)c1 * 16384 + b * 256 + k8);
  const short8 v2 = *(const short8*)(hb + (size_t)c2 * 16384 + b * 256 + k8);
  const short8 v3 = *(const short8*)(hb + (size_t)c3 * 16384 + b * 256 + k8);
  short8 ol, orr;
#pragma unroll
  for (int j = 0; j < 8; ++j) {
    ol[j] = (short)f2bf(bf2f((unsigned short)v0[j]) + bf2f((unsigned short)v1[j]));
    orr[j] = (short)f2bf(bf2f((unsigned short)v2[j]) + bf2f((unsigned short)v3[j]));
  }
  *(short8*)(lh + (size_t)r * 256 + k8) = ol;
  *(short8*)(rh + (size_t)r * 256 + k8) = orr;
}

// ---- reg-staged PF3 dbuf MFMA GEMM, 128x128 tile, 8 waves, LR=72 ----
// Swapped-operand MFMA: acc holds C^T fragments (m = lane&15, n = quad).
// EPI 0: gates (N=1280, K=768): sigmoid + vector scatter a2l/a2r/p1/p2/zb
// EPI 1: cell  (N=256,  K=768): tanh + hidden -> hb (bf16) + out (fp32)
template <int EPI>
static __device__ __forceinline__ void gemm_body(
    const unsigned short* __restrict__ Aseg0,
    const unsigned short* __restrict__ Aseg1,
    const unsigned short* __restrict__ Aseg2,
    const unsigned short* __restrict__ Wt, const float* __restrict__ bias,
    int rows, int row_off, int lvl_start, int NT, int nwg,
    const unsigned short* __restrict__ lh, const unsigned short* __restrict__ rh,
    unsigned short* __restrict__ a2l, unsigned short* __restrict__ a2r,
    unsigned short* __restrict__ p1, unsigned short* __restrict__ p2,
    unsigned short* __restrict__ zb, unsigned short* __restrict__ hb,
    float* __restrict__ out) {
  constexpr int NKT = 12;   // K-steps of 64 (K=768)
  constexpr int LR = 72;    // padded LDS row; 144 B = 9*16B
  int t = swz_t(blockIdx.x, nwg);
  int tm = t / NT, tn = t % NT;
  const int tid = threadIdx.x, lane = tid & 63, wave = tid >> 6;
  const int wr = wave >> 1, wcl = wave & 1;  // 4x2 wave grid; wave owns 32x64

  __shared__ unsigned short As[2][128 * LR];
  __shared__ unsigned short Bs[2][128 * LR];

  f32x4 acc[2][4];
#pragma unroll
  for (int i = 0; i < 2; ++i)
#pragma unroll
    for (int j = 0; j < 4; ++j) {
      f32x4 zv = {0.f, 0.f, 0.f, 0.f};
      acc[i][j] = zv;
    }

  const unsigned short* segs[3] = {Aseg0, Aseg1, Aseg2};
  const int srow = tid >> 3;
  const int scol = (tid & 7) * 8;

  short8 rva[3][2], rvb[3][2];

  auto LOADK = [&](int kt, int s) {
    int ko = (kt & 3) * 64;
    const unsigned short* segp = segs[kt >> 2];
#pragma unroll
    for (int i = 0; i < 2; ++i) {
      int row = srow + i * 64;
      rva[s][i] = *(const short8*)(segp + (size_t)(tm * 128 + row) * 256 + ko + scol);
      rvb[s][i] = *(const short8*)(Wt + (size_t)(tn * 128 + row) * 768 + kt * 64 + scol);
    }
  };
  auto WRITEK = [&](int s, int buf) {
#pragma unroll
    for (int i = 0; i < 2; ++i) {
      int row = srow + i * 64;
      *(short8*)(&As[buf][row * LR + scol]) = rva[s][i];
      *(short8*)(&Bs[buf][row * LR + scol]) = rvb[s][i];
    }
  };

  LOADK(0, 0);
  LOADK(1, 1);
  LOADK(2, 2);
  WRITEK(0, 0);
  bar_lgkm();

#pragma unroll
  for (int kt = 0; kt < NKT; ++kt) {
    const int cur = kt & 1;
    if (kt + 1 < NKT) WRITEK((kt + 1) % 3, cur ^ 1);
    if (kt + 3 < NKT) LOADK(kt + 3, kt % 3);
#pragma unroll
    for (int kk = 0; kk < 2; ++kk) {
      short8 af[2], bf[4];
#pragma unroll
      for (int mf = 0; mf < 2; ++mf)
        af[mf] = *(const short8*)(&As[cur][(wr * 32 + mf * 16 + (lane & 15)) * LR + kk * 32 + (lane >> 4) * 8]);
#pragma unroll
      for (int nf = 0; nf < 4; ++nf)
        bf[nf] = *(const short8*)(&Bs[cur][(wcl * 64 + nf * 16 + (lane & 15)) * LR + kk * 32 + (lane >> 4) * 8]);
#pragma unroll
      for (int mf = 0; mf < 2; ++mf)
#pragma unroll
        for (int nf = 0; nf < 4; ++nf)
          acc[mf][nf] = __builtin_amdgcn_mfma_f32_16x16x32_bf16(bf[nf], af[mf], acc[mf][nf], 0, 0, 0);
    }
    if (kt + 1 < NKT) bar_lgkm();
  }

  // ---- epilogue: C^T lane map: m-row = ..+(lane&15), n-col quad = ..+(lane>>4)*4+j ----
#pragma unroll
  for (int nf = 0; nf < 4; ++nf) {
    int colq = tn * 128 + wcl * 64 + nf * 16 + (lane >> 4) * 4;
    f32x4 bsv = *(const f32x4*)(bias + colq);
    if (EPI == 0) {
      int ck = colq >> 8;
      int gcq = colq & 255;
#pragma unroll
      for (int mf = 0; mf < 2; ++mf) {
        int r = tm * 128 + wr * 32 + mf * 16 + (lane & 15);
        if (r < rows) {
          size_t idx = (size_t)r * 256 + gcq;
          f32x4 s;
#pragma unroll
          for (int j = 0; j < 4; ++j) s[j] = sigmf(acc[mf][nf][j] + bsv[j]);
          short4v res;
          if (ck == 4) {
#pragma unroll
            for (int j = 0; j < 4; ++j) res[j] = (short)f2bf(s[j]);
            *(short4v*)(zb + idx) = res;
          } else {
            const unsigned short* src = (ck == 0 || ck == 2) ? lh : rh;
            short4v hv = *(const short4v*)(src + idx);
#pragma unroll
            for (int j = 0; j < 4; ++j) res[j] = (short)f2bf(s[j] * bf2f((unsigned short)hv[j]));
            if (ck == 0)      *(short4v*)(a2l + idx) = res;
            else if (ck == 1) *(short4v*)(a2r + idx) = res;
            else if (ck == 2) *(short4v*)(p1 + idx) = res;
            else              *(short4v*)(p2 + idx) = res;
          }
        }
      }
    } else {
#pragma unroll
      for (int mf = 0; mf < 2; ++mf) {
        int r = tm * 128 + wr * 32 + mf * 16 + (lane & 15);
        if (r < rows) {
          size_t idx = (size_t)r * 256 + colq;
          short4v p1v = *(const short4v*)(p1 + idx);
          short4v p2v = *(const short4v*)(p2 + idx);
          short4v zbv = *(const short4v*)(zb + idx);
          int gr = row_off + r;
          int node = lvl_start + (gr >> 6);
          int b = gr & 63;
          short4v hv;
          float4 ov;
#pragma unroll
          for (int j = 0; j < 4; ++j) {
            float cell = tanhf_(acc[mf][nf][j] + bsv[j]);
            float hid = bf2f((unsigned short)p1v[j]) + bf2f((unsigned short)p2v[j]) +
                        bf2f((unsigned short)zbv[j]) * cell;
            hv[j] = (short)f2bf(hid);
            ((float*)&ov)[j] = hid;
          }
          *(short4v*)(hb + (size_t)node * 16384 + b * 256 + colq) = hv;
          int jj = node ? (node - 1) : 1023;
          *(float4*)(out + (size_t)b * 262144 + (size_t)jj * 256 + colq) = ov;
          if (node == 0)
            *(float4*)(out + 16777216 + (size_t)b * 256 + colq) = ov;
        }
      }
    }
  }
}

__global__ __launch_bounds__(512, 4) void k_gates(
    const unsigned short* __restrict__ A0, const unsigned short* __restrict__ A1,
    const unsigned short* __restrict__ A2, const unsigned short* __restrict__ Wt,
    const float* __restrict__ bias, int rows, int row_off, int lvl_start, int nwg,
    const unsigned short* __restrict__ lh, const unsigned short* __restrict__ rh,
    unsigned short* __restrict__ a2l, unsigned short* __restrict__ a2r,
    unsigned short* __restrict__ p1, unsigned short* __restrict__ p2,
    unsigned short* __restrict__ zb) {
  gemm_body<0>(A0, A1, A2, Wt, bias, rows, row_off, lvl_start, 10, nwg,
               lh, rh, a2l, a2r, p1, p2, zb, nullptr, nullptr);
}

__global__ __launch_bounds__(512, 4) void k_cell(
    const unsigned short* __restrict__ A0, const unsigned short* __restrict__ A1,
    const unsigned short* __restrict__ A2, const unsigned short* __restrict__ Wt,
    const float* __restrict__ bias, int rows, int row_off, int lvl_start, int nwg,
    const unsigned short* __restrict__ p1, const unsigned short* __restrict__ p2,
    const unsigned short* __restrict__ zb, unsigned short* __restrict__ hb,
    float* __restrict__ out) {
  gemm_body<1>(A0, A1, A2, Wt, bias, rows, row_off, lvl_start, 2, nwg,
               nullptr, nullptr, nullptr, nullptr, (unsigned short*)p1,
               (unsigned short*)p2, (unsigned short*)zb, hb, out);
}

// ---- leaf v2: A-stationary. Block = 128 rows, loops all 4 tn (N=512).
// A-frags (fp32 X -> bf16) in registers for full K=256; only B in LDS.
// Wave = 16-row strip; all waves share B frags (LDS broadcast).
__global__ __launch_bounds__(512, 4) void k_leaf(
    const float* __restrict__ Af, const unsigned short* __restrict__ Wl,
    const float* __restrict__ bg, const float* __restrict__ bc, int nwg,
    unsigned short* __restrict__ hb, float* __restrict__ out) {
  constexpr int LR = 72;
  int tm = swz_t(blockIdx.x, nwg);     // 384 blocks
  const int tid = threadIdx.x, lane = tid & 63, wave = tid >> 6;

  __shared__ unsigned short Bs[2][128 * LR];   // 36864 B total

  // A fragments for the whole K=256: afr[kk], kk=0..7 (row fixed per lane)
  const int arow = tm * 128 + wave * 16 + (lane & 15);
  short8 afr[8];
  {
    const float* ap = Af + (size_t)arow * 256 + (lane >> 4) * 8;
#pragma unroll
    for (int kk = 0; kk < 8; ++kk) {
      f32x4 f0 = *(const f32x4*)(ap + kk * 32);
      f32x4 f1 = *(const f32x4*)(ap + kk * 32 + 4);
      short8 v;
#pragma unroll
      for (int j = 0; j < 4; ++j) {
        v[j] = (short)f2bf(f0[j]);
        v[j + 4] = (short)f2bf(f1[j]);
      }
      afr[kk] = v;
    }
  }

  const int srow = tid >> 3;        // 0..63 (and +64)
  const int scol = (tid & 7) * 8;
  short8 rvb[2][2];                 // PF2 B staging sets

  auto LOADB = [&](int s, int set) {  // s = tn*4 + kt
    int tn = s >> 2, kt = s & 3;
#pragma unroll
    for (int i = 0; i < 2; ++i)
      rvb[set][i] = *(const short8*)(Wl + (size_t)(tn * 128 + srow + i * 64) * 256 + kt * 64 + scol);
  };
  auto WRITEB = [&](int set, int buf) {
#pragma unroll
    for (int i = 0; i < 2; ++i)
      *(short8*)(&Bs[buf][(srow + i * 64) * LR + scol]) = rvb[set][i];
  };

  LOADB(0, 0);
  LOADB(1, 1);
  WRITEB(0, 0);
  bar_lgkm();

  f32x4 acc[8];

#pragma unroll
  for (int s = 0; s < 16; ++s) {
    const int cur = s & 1;
    const int kt = s & 3;
    if (kt == 0) {
#pragma unroll
      for (int nf = 0; nf < 8; ++nf) {
        f32x4 zv = {0.f, 0.f, 0.f, 0.f};
        acc[nf] = zv;
      }
    }
    if (s + 1 < 16) WRITEB((s + 1) & 1, cur ^ 1);  // counted vmcnt on tile s+1
    if (s + 2 < 16) LOADB(s + 2, s & 1);           // refill freed set
#pragma unroll
    for (int kk2 = 0; kk2 < 2; ++kk2) {
      int kk = kt * 2 + kk2;
      short8 bf[8];
#pragma unroll
      for (int nf = 0; nf < 8; ++nf)
        bf[nf] = *(const short8*)(&Bs[cur][(nf * 16 + (lane & 15)) * LR + kk2 * 32 + (lane >> 4) * 8]);
#pragma unroll
      for (int nf = 0; nf < 8; ++nf)
        acc[nf] = __builtin_amdgcn_mfma_f32_16x16x32_bf16(bf[nf], afr[kk], acc[nf], 0, 0, 0);
    }
    if (s + 1 < 16) bar_lgkm();
    if (kt == 3) {
      // epilogue for this tn: even nf = z, odd = c (interleaved Wl)
      int tn = s >> 2;
      int node = 256 + (arow >> 6), b = arow & 63;
#pragma unroll
      for (int nfp = 0; nfp < 4; ++nfp) {
        int hcq = (tn * 4 + nfp) * 16 + (lane >> 4) * 4;
        f32x4 bzv = *(const f32x4*)(bg + 1024 + hcq);
        f32x4 bcv = *(const f32x4*)(bc + hcq);
        short4v hv;
        float4 ov;
#pragma unroll
        for (int j = 0; j < 4; ++j) {
          float h = sigmf(acc[2 * nfp][j] + bzv[j]) * tanhf_(acc[2 * nfp + 1][j] + bcv[j]);
          hv[j] = (short)f2bf(h);
          ((float*)&ov)[j] = h;
        }
        *(short4v*)(hb + (size_t)node * 16384 + b * 256 + hcq) = hv;
        *(float4*)(out + (size_t)b * 262144 + (size_t)(node - 1) * 256 + hcq) = ov;
      }
    }
  }
}

extern "C" void kernel_launch(void* const* d_in, const int* in_sizes, int n_in,
                              void* d_out, int out_size, void* d_ws, size_t ws_size,
                              hipStream_t stream) {
  const float* inputs = (const float*)d_in[0];
  const float* W_gih = (const float*)d_in[3];
  const float* b_gih = (const float*)d_in[4];
  const float* W_glh = (const float*)d_in[5];
  const float* W_grh = (const float*)d_in[6];
  const float* W_cih = (const float*)d_in[7];
  const float* b_cih = (const float*)d_in[8];
  const float* W_clh = (const float*)d_in[9];
  const float* W_crh = (const float*)d_in[10];
  float* out = (float*)d_out;

  char* ws = (char*)d_ws;
  size_t cur = 0;
  auto alloc = [&](size_t bytes) -> char* {
    char* p = ws + cur;
    cur += (bytes + 255) & ~(size_t)255;
    return p;
  };

  // xb holds only internal x rows (0..16383) + pad for tail-block overreads
  unsigned short* xb = (unsigned short*)alloc((size_t)(16384 + 128) * 256 * 2);
  unsigned short* hb = (unsigned short*)alloc((size_t)1025 * 16384 * 2);
  unsigned short* Wg = (unsigned short*)alloc((size_t)1280 * 768 * 2);
  unsigned short* Wc = (unsigned short*)alloc((size_t)256 * 768 * 2);
  unsigned short* Wl = (unsigned short*)alloc((size_t)512 * 256 * 2);

  size_t rem = (ws_size > cur) ? (ws_size - cur) : 0;
  long long rcap = (long long)(rem / (7 * 512 + 64));
  rcap = (rcap / 128) * 128;
  int Rchunk = (int)((rcap < 11008) ? rcap : 11008);  // max internal level = 10944 rows
  if (Rchunk < 128) Rchunk = 128;

  unsigned short* lh  = (unsigned short*)alloc((size_t)Rchunk * 512);
  unsigned short* rh  = (unsigned short*)alloc((size_t)Rchunk * 512);
  unsigned short* a2l = (unsigned short*)alloc((size_t)Rchunk * 512);
  unsigned short* a2r = (unsigned short*)alloc((size_t)Rchunk * 512);
  unsigned short* p1  = (unsigned short*)alloc((size_t)Rchunk * 512);
  unsigned short* p2  = (unsigned short*)alloc((size_t)Rchunk * 512);
  unsigned short* zb  = (unsigned short*)alloc((size_t)Rchunk * 512);

  k_pre<<<5120, 256, 0, stream>>>(inputs, W_gih, W_glh, W_grh, W_cih, W_clh, W_crh,
                                  xb, Wg, Wc, Wl, hb);

  // leaves (nodes 256..1023): 49152 rows; A-stationary blocks (all N per block)
  k_leaf<<<384, 512, 0, stream>>>(inputs + (size_t)16384 * 256, Wl, b_gih, b_cih, 384, hb, out);

  // internal levels bottom-up
  static const int LSi[5] = {0, 1, 5, 21, 85};
  static const int LCi[5] = {1, 4, 16, 64, 171};

  for (int d = 4; d >= 0; --d) {
    int rows_lvl = LCi[d] * 64;
    for (int off = 0; off < rows_lvl; off += Rchunk) {
      int rows = rows_lvl - off;
      if (rows > Rchunk) rows = Rchunk;
      int tmn = (rows + 127) / 128;
      int pgrid = (rows * 32 + 255) / 256;
      k_prep<<<pgrid, 256, 0, stream>>>(hb, lh, rh, rows, off, LSi[d]);
      const unsigned short* xseg = xb + (size_t)(LSi[d] * 64 + off) * 256;
      int nwg_g = tmn * 10;
      k_gates<<<nwg_g, 512, 0, stream>>>(xseg, lh, rh, Wg, b_gih, rows, off, LSi[d], nwg_g,
                                         lh, rh, a2l, a2r, p1, p2, zb);
      int nwg_c = tmn * 2;
      k_cell<<<nwg_c, 512, 0, stream>>>(xseg, a2l, a2r, Wc, b_cih, rows, off, LSi[d], nwg_c,
                                        p1, p2, zb, hb, out);
    }
  }
}

// Round 16
// 254.855 us; speedup vs baseline: 1.0419x; 1.0419x over previous
//
#include <hip/hip_runtime.h>

// DTTreeGRU: L=1024, B=64, D=256, H=256, K=4 (tree arity)
// Heap tree: internal nodes 0..255, leaves 256..1023 (children 4n+1..4n+4).
// Internal levels (bottom-up): starts {0,1,5,21,85}, counts {1,4,16,64,171}.
// Leaves: lh=rh=0 -> h = sigmoid(x@Wz^T+bz) * tanh(x@Wc^T+bc): one GEMM over
// interleaved Wl (512 x 256; 16-col z/c groups so z,c pair within one wave).
//
// r16 = r14 (best: 255.7us) + BK=128 latency variant for small dispatches.
// r15 lesson: leaf A-stationary regressed (grid 384 -> 1.5 blk/CU imbalance,
// more LDS traffic) -> reverted. r14 ledger: L0-L3 + cell dispatches are
// LATENCY-bound (~1 blk/CU, runtime = 12 K-steps x per-step stall). BK=128
// halves the K-step count (NKT=6, LR=136 odd-multiple pad, 139KB LDS,
// 1 blk/CU - irrelevant since whole level is resident). Used for gates when
// nwg<=256 (L0-L2) and all cell launches (<=172 blocks).

#define L_TOT 1024

typedef __attribute__((ext_vector_type(8))) short short8;
typedef __attribute__((ext_vector_type(4))) short short4v;
typedef __attribute__((ext_vector_type(4))) float f32x4;

static __device__ __forceinline__ float bf2f(unsigned short u) {
  unsigned int x = ((unsigned int)u) << 16;
  return __builtin_bit_cast(float, x);
}
static __device__ __forceinline__ unsigned short f2bf(float f) {
  unsigned int u = __builtin_bit_cast(unsigned int, f);
  u += 0x7fffu + ((u >> 16) & 1u);
  return (unsigned short)(u >> 16);
}
static __device__ __forceinline__ float sigmf(float x) { return 1.0f / (1.0f + __expf(-x)); }
static __device__ __forceinline__ float tanhf_(float x) { return 2.0f / (1.0f + __expf(-2.0f * x)) - 1.0f; }

// lgkm-only barrier: LDS ops visible, global loads stay in flight
static __device__ __forceinline__ void bar_lgkm() {
  asm volatile("s_waitcnt lgkmcnt(0)" ::: "memory");
  __builtin_amdgcn_s_barrier();
  __builtin_amdgcn_sched_barrier(0);
}

// bijective XCD swizzle (m204): contiguous logical range per XCD
static __device__ __forceinline__ int swz_t(int orig, int nwg) {
  int q = nwg >> 3, r = nwg & 7, x = orig & 7, s = orig >> 3;
  return (x < r ? x * (q + 1) : r * (q + 1) + (x - r) * q) + s;
}

// ---- prologue: convert INTERNAL x rows -> bf16, build weights, zero pad ----
__global__ __launch_bounds__(256) void k_pre(
    const float* __restrict__ in,
    const float* __restrict__ Wgih, const float* __restrict__ Wglh, const float* __restrict__ Wgrh,
    const float* __restrict__ Wcih, const float* __restrict__ Wclh, const float* __restrict__ Wcrh,
    unsigned short* __restrict__ xb, unsigned short* __restrict__ Wg,
    unsigned short* __restrict__ Wc, unsigned short* __restrict__ Wl,
    unsigned short* __restrict__ hb) {
  int t = blockIdx.x * 256 + threadIdx.x;
  if (t < 524288) {
    const float* s = in + (size_t)t * 8;
    short8 v;
#pragma unroll
    for (int j = 0; j < 8; ++j) v[j] = (short)f2bf(s[j]);
    *(short8*)(xb + (size_t)t * 8) = v;
  }
  const int NG = 1280 * 768;
  const int NC = 256 * 768;
  const int NL = 512 * 256;
  if (t < NG) {
    int g = t / 768, k = t % 768;
    float v = (k < 256) ? Wgih[g * 256 + k] : ((k < 512) ? Wglh[g * 256 + k - 256] : Wgrh[g * 256 + k - 512]);
    Wg[t] = f2bf(v);
  } else if (t < NG + NC) {
    int t2 = t - NG;
    int g = t2 / 768, k = t2 % 768;
    float v = (k < 256) ? Wcih[g * 256 + k] : ((k < 512) ? Wclh[g * 256 + k - 256] : Wcrh[g * 256 + k - 512]);
    Wc[t2] = f2bf(v);
  } else if (t < NG + NC + NL) {
    int t2 = t - NG - NC;
    int n = t2 >> 8, k = t2 & 255;
    int g = n >> 4;
    int hc = (g >> 1) * 16 + (n & 15);
    float v = (g & 1) ? Wcih[hc * 256 + k] : Wgih[(1024 + hc) * 256 + k];
    Wl[t2] = f2bf(v);
  }
  if (t < 16384) hb[(size_t)1024 * 16384 + t] = 0;  // zero slot
}

// ---- per-level: lh = h[c0]+h[c1], rh = h[c2]+h[c3]; 8 elems/thread ----
__global__ __launch_bounds__(256) void k_prep(const unsigned short* __restrict__ hb,
                                              unsigned short* __restrict__ lh,
                                              unsigned short* __restrict__ rh,
                                              int rows, int row_off, int lvl_start) {
  int t = blockIdx.x * 256 + threadIdx.x;
  if (t >= rows * 32) return;
  int r = t >> 5, k8 = (t & 31) << 3;
  int gr = row_off + r;
  int node = lvl_start + (gr >> 6);
  int b = gr & 63;
  int cb = 4 * node + 1;
  int c0 = cb, c1 = cb + 1, c2 = cb + 2, c3 = cb + 3;
  c0 = (c0 < L_TOT) ? c0 : L_TOT;
  c1 = (c1 < L_TOT) ? c1 : L_TOT;
  c2 = (c2 < L_TOT) ? c2 : L_TOT;
  c3 = (c3 < L_TOT) ? c3 : L_TOT;
  const short8 v0 = *(const short8*)(hb + (size_t)c0 * 16384 + b * 256 + k8);
  const short8 v1 = *(const short8*)(hb + (size_t)c1 * 16384 + b * 256 + k8);
  const short8 v2 = *(const short8*)(hb + (size_t)c2 * 16384 + b * 256 + k8);
  const short8 v3 = *(const short8*)(hb + (size_t)c3 * 16384 + b * 256 + k8);
  short8 ol, orr;
#pragma unroll
  for (int j = 0; j < 8; ++j) {
    ol[j] = (short)f2bf(bf2f((unsigned short)v0[j]) + bf2f((unsigned short)v1[j]));
    orr[j] = (short)f2bf(bf2f((unsigned short)v2[j]) + bf2f((unsigned short)v3[j]));
  }
  *(short8*)(lh + (size_t)r * 256 + k8) = ol;
  *(short8*)(rh + (size_t)r * 256 + k8) = orr;
}

// ---- reg-staged PF3 dbuf MFMA GEMM, 128x128 tile, 8 waves, BK=64, LR=72 ----
// Swapped-operand MFMA: acc holds C^T fragments (m = lane&15, n = quad).
// EPI 0: gates (N=1280, K=768) | EPI 1: cell (N=256, K=768) | EPI 2: leaf
template <int EPI>
static __device__ __forceinline__ void gemm_body(
    const float* __restrict__ Af,
    const unsigned short* __restrict__ Aseg0,
    const unsigned short* __restrict__ Aseg1,
    const unsigned short* __restrict__ Aseg2,
    const unsigned short* __restrict__ Wt, const float* __restrict__ bias,
    const float* __restrict__ bias2,
    int rows, int row_off, int lvl_start, int NT, int nwg,
    const unsigned short* __restrict__ lh, const unsigned short* __restrict__ rh,
    unsigned short* __restrict__ a2l, unsigned short* __restrict__ a2r,
    unsigned short* __restrict__ p1, unsigned short* __restrict__ p2,
    unsigned short* __restrict__ zb, unsigned short* __restrict__ hb,
    float* __restrict__ out) {
  constexpr int NKT = (EPI == 2) ? 4 : 12;
  constexpr int WSTRIDE = (EPI == 2) ? 256 : 768;
  constexpr int LR = 72;
  int t = swz_t(blockIdx.x, nwg);
  int tm = t / NT, tn = t % NT;
  const int tid = threadIdx.x, lane = tid & 63, wave = tid >> 6;
  const int wr = wave >> 1, wcl = wave & 1;

  __shared__ unsigned short As[2][128 * LR];
  __shared__ unsigned short Bs[2][128 * LR];

  f32x4 acc[2][4];
#pragma unroll
  for (int i = 0; i < 2; ++i)
#pragma unroll
    for (int j = 0; j < 4; ++j) {
      f32x4 zv = {0.f, 0.f, 0.f, 0.f};
      acc[i][j] = zv;
    }

  const unsigned short* segs[3] = {Aseg0, Aseg1, Aseg2};
  const int srow = tid >> 3;
  const int scol = (tid & 7) * 8;

  short8 rva[3][2], rvb[3][2];
  f32x4 fva[3][2][2];

  auto LOADK = [&](int kt, int s) {
    int ko = (kt & 3) * 64;
#pragma unroll
    for (int i = 0; i < 2; ++i) {
      int row = srow + i * 64;
      if (EPI == 2) {
        const float* ap = Af + (size_t)(tm * 128 + row) * 256 + ko + scol;
        fva[s][i][0] = *(const f32x4*)(ap);
        fva[s][i][1] = *(const f32x4*)(ap + 4);
      } else {
        const unsigned short* segp = segs[kt >> 2];
        rva[s][i] = *(const short8*)(segp + (size_t)(tm * 128 + row) * 256 + ko + scol);
      }
      rvb[s][i] = *(const short8*)(Wt + (size_t)(tn * 128 + row) * WSTRIDE + kt * 64 + scol);
    }
  };
  auto WRITEK = [&](int s, int buf) {
#pragma unroll
    for (int i = 0; i < 2; ++i) {
      int row = srow + i * 64;
      short8 v;
      if (EPI == 2) {
#pragma unroll
        for (int j = 0; j < 4; ++j) {
          v[j] = (short)f2bf(fva[s][i][0][j]);
          v[j + 4] = (short)f2bf(fva[s][i][1][j]);
        }
      } else {
        v = rva[s][i];
      }
      *(short8*)(&As[buf][row * LR + scol]) = v;
      *(short8*)(&Bs[buf][row * LR + scol]) = rvb[s][i];
    }
  };

  LOADK(0, 0);
  LOADK(1, 1);
  if (NKT > 2) LOADK(2, 2);
  WRITEK(0, 0);
  bar_lgkm();

#pragma unroll
  for (int kt = 0; kt < NKT; ++kt) {
    const int cur = kt & 1;
    if (kt + 1 < NKT) WRITEK((kt + 1) % 3, cur ^ 1);
    if (kt + 3 < NKT) LOADK(kt + 3, kt % 3);
#pragma unroll
    for (int kk = 0; kk < 2; ++kk) {
      short8 af[2], bf[4];
#pragma unroll
      for (int mf = 0; mf < 2; ++mf)
        af[mf] = *(const short8*)(&As[cur][(wr * 32 + mf * 16 + (lane & 15)) * LR + kk * 32 + (lane >> 4) * 8]);
#pragma unroll
      for (int nf = 0; nf < 4; ++nf)
        bf[nf] = *(const short8*)(&Bs[cur][(wcl * 64 + nf * 16 + (lane & 15)) * LR + kk * 32 + (lane >> 4) * 8]);
#pragma unroll
      for (int mf = 0; mf < 2; ++mf)
#pragma unroll
        for (int nf = 0; nf < 4; ++nf)
          acc[mf][nf] = __builtin_amdgcn_mfma_f32_16x16x32_bf16(bf[nf], af[mf], acc[mf][nf], 0, 0, 0);
    }
    if (kt + 1 < NKT) bar_lgkm();
  }

  // ---- epilogue: C^T lane map ----
  if (EPI == 2) {
#pragma unroll
    for (int nfp = 0; nfp < 2; ++nfp) {
      int nz = nfp * 2;
      int g = tn * 8 + wcl * 4 + nz;
      int hcq = (g >> 1) * 16 + (lane >> 4) * 4;
      f32x4 bzv = *(const f32x4*)(bias + 1024 + hcq);
      f32x4 bcv = *(const f32x4*)(bias2 + hcq);
#pragma unroll
      for (int mf = 0; mf < 2; ++mf) {
        int r = tm * 128 + wr * 32 + mf * 16 + (lane & 15);
        int node = 256 + (r >> 6), b = r & 63;
        short4v hv;
        float4 ov;
#pragma unroll
        for (int j = 0; j < 4; ++j) {
          float h = sigmf(acc[mf][nz][j] + bzv[j]) * tanhf_(acc[mf][nz + 1][j] + bcv[j]);
          hv[j] = (short)f2bf(h);
          ((float*)&ov)[j] = h;
        }
        *(short4v*)(hb + (size_t)node * 16384 + b * 256 + hcq) = hv;
        *(float4*)(out + (size_t)b * 262144 + (size_t)(node - 1) * 256 + hcq) = ov;
      }
    }
    return;
  }
#pragma unroll
  for (int nf = 0; nf < 4; ++nf) {
    int colq = tn * 128 + wcl * 64 + nf * 16 + (lane >> 4) * 4;
    f32x4 bsv = *(const f32x4*)(bias + colq);
    if (EPI == 0) {
      int ck = colq >> 8;
      int gcq = colq & 255;
#pragma unroll
      for (int mf = 0; mf < 2; ++mf) {
        int r = tm * 128 + wr * 32 + mf * 16 + (lane & 15);
        if (r < rows) {
          size_t idx = (size_t)r * 256 + gcq;
          f32x4 s;
#pragma unroll
          for (int j = 0; j < 4; ++j) s[j] = sigmf(acc[mf][nf][j] + bsv[j]);
          short4v res;
          if (ck == 4) {
#pragma unroll
            for (int j = 0; j < 4; ++j) res[j] = (short)f2bf(s[j]);
            *(short4v*)(zb + idx) = res;
          } else {
            const unsigned short* src = (ck == 0 || ck == 2) ? lh : rh;
            short4v hv = *(const short4v*)(src + idx);
#pragma unroll
            for (int j = 0; j < 4; ++j) res[j] = (short)f2bf(s[j] * bf2f((unsigned short)hv[j]));
            if (ck == 0)      *(short4v*)(a2l + idx) = res;
            else if (ck == 1) *(short4v*)(a2r + idx) = res;
            else if (ck == 2) *(short4v*)(p1 + idx) = res;
            else              *(short4v*)(p2 + idx) = res;
          }
        }
      }
    } else {
#pragma unroll
      for (int mf = 0; mf < 2; ++mf) {
        int r = tm * 128 + wr * 32 + mf * 16 + (lane & 15);
        if (r < rows) {
          size_t idx = (size_t)r * 256 + colq;
          short4v p1v = *(const short4v*)(p1 + idx);
          short4v p2v = *(const short4v*)(p2 + idx);
          short4v zbv = *(const short4v*)(zb + idx);
          int gr = row_off + r;
          int node = lvl_start + (gr >> 6);
          int b = gr & 63;
          short4v hv;
          float4 ov;
#pragma unroll
          for (int j = 0; j < 4; ++j) {
            float cell = tanhf_(acc[mf][nf][j] + bsv[j]);
            float hid = bf2f((unsigned short)p1v[j]) + bf2f((unsigned short)p2v[j]) +
                        bf2f((unsigned short)zbv[j]) * cell;
            hv[j] = (short)f2bf(hid);
            ((float*)&ov)[j] = hid;
          }
          *(short4v*)(hb + (size_t)node * 16384 + b * 256 + colq) = hv;
          int jj = node ? (node - 1) : 1023;
          *(float4*)(out + (size_t)b * 262144 + (size_t)jj * 256 + colq) = ov;
          if (node == 0)
            *(float4*)(out + 16777216 + (size_t)b * 256 + colq) = ov;
        }
      }
    }
  }
}

// ---- BK=128 latency variant: NKT=6, PF2, LR=136 (odd-multiple pad),
// LDS 139KB -> 1 block/CU. For small (latency-bound) dispatches only.
template <int EPI>
static __device__ __forceinline__ void gemm_body128(
    const unsigned short* __restrict__ Aseg0,
    const unsigned short* __restrict__ Aseg1,
    const unsigned short* __restrict__ Aseg2,
    const unsigned short* __restrict__ Wt, const float* __restrict__ bias,
    int rows, int row_off, int lvl_start, int NT, int nwg,
    const unsigned short* __restrict__ lh, const unsigned short* __restrict__ rh,
    unsigned short* __restrict__ a2l, unsigned short* __restrict__ a2r,
    unsigned short* __restrict__ p1, unsigned short* __restrict__ p2,
    unsigned short* __restrict__ zb, unsigned short* __restrict__ hb,
    float* __restrict__ out) {
  constexpr int NKT = 6;     // K-steps of 128
  constexpr int LR = 136;    // 272 B = 17*16B (odd multiple -> rotating banks)
  int t = swz_t(blockIdx.x, nwg);
  int tm = t / NT, tn = t % NT;
  const int tid = threadIdx.x, lane = tid & 63, wave = tid >> 6;
  const int wr = wave >> 1, wcl = wave & 1;

  __shared__ unsigned short As[2][128 * LR];
  __shared__ unsigned short Bs[2][128 * LR];

  f32x4 acc[2][4];
#pragma unroll
  for (int i = 0; i < 2; ++i)
#pragma unroll
    for (int j = 0; j < 4; ++j) {
      f32x4 zv = {0.f, 0.f, 0.f, 0.f};
      acc[i][j] = zv;
    }

  const unsigned short* segs[3] = {Aseg0, Aseg1, Aseg2};

  short8 rva[2][4], rvb[2][4];   // PF2 sets; 4 chunks/thread/array

  auto LOADK = [&](int kt, int s) {
    const unsigned short* segp = segs[kt >> 1];
    int ko = (kt & 1) * 128;
#pragma unroll
    for (int i = 0; i < 4; ++i) {
      int ch = tid + 512 * i;
      int row = ch >> 4;
      int col = (ch & 15) * 8;
      rva[s][i] = *(const short8*)(segp + (size_t)(tm * 128 + row) * 256 + ko + col);
      rvb[s][i] = *(const short8*)(Wt + (size_t)(tn * 128 + row) * 768 + kt * 128 + col);
    }
  };
  auto WRITEK = [&](int s, int buf) {
#pragma unroll
    for (int i = 0; i < 4; ++i) {
      int ch = tid + 512 * i;
      int row = ch >> 4;
      int col = (ch & 15) * 8;
      *(short8*)(&As[buf][row * LR + col]) = rva[s][i];
      *(short8*)(&Bs[buf][row * LR + col]) = rvb[s][i];
    }
  };

  LOADK(0, 0);
  LOADK(1, 1);
  WRITEK(0, 0);
  bar_lgkm();

#pragma unroll
  for (int kt = 0; kt < NKT; ++kt) {
    const int cur = kt & 1;
    if (kt + 1 < NKT) WRITEK((kt + 1) & 1, cur ^ 1);  // counted vmcnt on kt+1
    if (kt + 2 < NKT) LOADK(kt + 2, kt & 1);          // refill freed set
#pragma unroll
    for (int kk = 0; kk < 4; ++kk) {
      short8 af[2], bf[4];
#pragma unroll
      for (int mf = 0; mf < 2; ++mf)
        af[mf] = *(const short8*)(&As[cur][(wr * 32 + mf * 16 + (lane & 15)) * LR + kk * 32 + (lane >> 4) * 8]);
#pragma unroll
      for (int nf = 0; nf < 4; ++nf)
        bf[nf] = *(const short8*)(&Bs[cur][(wcl * 64 + nf * 16 + (lane & 15)) * LR + kk * 32 + (lane >> 4) * 8]);
#pragma unroll
      for (int mf = 0; mf < 2; ++mf)
#pragma unroll
        for (int nf = 0; nf < 4; ++nf)
          acc[mf][nf] = __builtin_amdgcn_mfma_f32_16x16x32_bf16(bf[nf], af[mf], acc[mf][nf], 0, 0, 0);
    }
    if (kt + 1 < NKT) bar_lgkm();
  }

  // ---- epilogue (same as BK=64) ----
#pragma unroll
  for (int nf = 0; nf < 4; ++nf) {
    int colq = tn * 128 + wcl * 64 + nf * 16 + (lane >> 4) * 4;
    f32x4 bsv = *(const f32x4*)(bias + colq);
    if (EPI == 0) {
      int ck = colq >> 8;
      int gcq = colq & 255;
#pragma unroll
      for (int mf = 0; mf < 2; ++mf) {
        int r = tm * 128 + wr * 32 + mf * 16 + (lane & 15);
        if (r < rows) {
          size_t idx = (size_t)r * 256 + gcq;
          f32x4 s;
#pragma unroll
          for (int j = 0; j < 4; ++j) s[j] = sigmf(acc[mf][nf][j] + bsv[j]);
          short4v res;
          if (ck == 4) {
#pragma unroll
            for (int j = 0; j < 4; ++j) res[j] = (short)f2bf(s[j]);
            *(short4v*)(zb + idx) = res;
          } else {
            const unsigned short* src = (ck == 0 || ck == 2) ? lh : rh;
            short4v hv = *(const short4v*)(src + idx);
#pragma unroll
            for (int j = 0; j < 4; ++j) res[j] = (short)f2bf(s[j] * bf2f((unsigned short)hv[j]));
            if (ck == 0)      *(short4v*)(a2l + idx) = res;
            else if (ck == 1) *(short4v*)(a2r + idx) = res;
            else if (ck == 2) *(short4v*)(p1 + idx) = res;
            else              *(short4v*)(p2 + idx) = res;
          }
        }
      }
    } else {
#pragma unroll
      for (int mf = 0; mf < 2; ++mf) {
        int r = tm * 128 + wr * 32 + mf * 16 + (lane & 15);
        if (r < rows) {
          size_t idx = (size_t)r * 256 + colq;
          short4v p1v = *(const short4v*)(p1 + idx);
          short4v p2v = *(const short4v*)(p2 + idx);
          short4v zbv = *(const short4v*)(zb + idx);
          int gr = row_off + r;
          int node = lvl_start + (gr >> 6);
          int b = gr & 63;
          short4v hv;
          float4 ov;
#pragma unroll
          for (int j = 0; j < 4; ++j) {
            float cell = tanhf_(acc[mf][nf][j] + bsv[j]);
            float hid = bf2f((unsigned short)p1v[j]) + bf2f((unsigned short)p2v[j]) +
                        bf2f((unsigned short)zbv[j]) * cell;
            hv[j] = (short)f2bf(hid);
            ((float*)&ov)[j] = hid;
          }
          *(short4v*)(hb + (size_t)node * 16384 + b * 256 + colq) = hv;
          int jj = node ? (node - 1) : 1023;
          *(float4*)(out + (size_t)b * 262144 + (size_t)jj * 256 + colq) = ov;
          if (node == 0)
            *(float4*)(out + 16777216 + (size_t)b * 256 + colq) = ov;
        }
      }
    }
  }
}

__global__ __launch_bounds__(512, 4) void k_gates(
    const unsigned short* __restrict__ A0, const unsigned short* __restrict__ A1,
    const unsigned short* __restrict__ A2, const unsigned short* __restrict__ Wt,
    const float* __restrict__ bias, int rows, int row_off, int lvl_start, int nwg,
    const unsigned short* __restrict__ lh, const unsigned short* __restrict__ rh,
    unsigned short* __restrict__ a2l, unsigned short* __restrict__ a2r,
    unsigned short* __restrict__ p1, unsigned short* __restrict__ p2,
    unsigned short* __restrict__ zb) {
  gemm_body<0>(nullptr, A0, A1, A2, Wt, bias, nullptr, rows, row_off, lvl_start, 10, nwg,
               lh, rh, a2l, a2r, p1, p2, zb, nullptr, nullptr);
}

__global__ __launch_bounds__(512, 2) void k_gates_s(
    const unsigned short* __restrict__ A0, const unsigned short* __restrict__ A1,
    const unsigned short* __restrict__ A2, const unsigned short* __restrict__ Wt,
    const float* __restrict__ bias, int rows, int row_off, int lvl_start, int nwg,
    const unsigned short* __restrict__ lh, const unsigned short* __restrict__ rh,
    unsigned short* __restrict__ a2l, unsigned short* __restrict__ a2r,
    unsigned short* __restrict__ p1, unsigned short* __restrict__ p2,
    unsigned short* __restrict__ zb) {
  gemm_body128<0>(A0, A1, A2, Wt, bias, rows, row_off, lvl_start, 10, nwg,
                  lh, rh, a2l, a2r, p1, p2, zb, nullptr, nullptr);
}

__global__ __launch_bounds__(512, 2) void k_cell_s(
    const unsigned short* __restrict__ A0, const unsigned short* __restrict__ A1,
    const unsigned short* __restrict__ A2, const unsigned short* __restrict__ Wt,
    const float* __restrict__ bias, int rows, int row_off, int lvl_start, int nwg,
    const unsigned short* __restrict__ p1, const unsigned short* __restrict__ p2,
    const unsigned short* __restrict__ zb, unsigned short* __restrict__ hb,
    float* __restrict__ out) {
  gemm_body128<1>(A0, A1, A2, Wt, bias, rows, row_off, lvl_start, 2, nwg,
                  nullptr, nullptr, nullptr, nullptr, (unsigned short*)p1,
                  (unsigned short*)p2, (unsigned short*)zb, hb, out);
}

__global__ __launch_bounds__(512, 4) void k_leaf(
    const float* __restrict__ X, const unsigned short* __restrict__ Wl,
    const float* __restrict__ bg, const float* __restrict__ bc, int nwg,
    unsigned short* __restrict__ hb, float* __restrict__ out) {
  gemm_body<2>(X, nullptr, nullptr, nullptr, Wl, bg, bc, 49152, 0, 0, 4, nwg,
               nullptr, nullptr, nullptr, nullptr, nullptr, nullptr, nullptr, hb, out);
}

extern "C" void kernel_launch(void* const* d_in, const int* in_sizes, int n_in,
                              void* d_out, int out_size, void* d_ws, size_t ws_size,
                              hipStream_t stream) {
  const float* inputs = (const float*)d_in[0];
  const float* W_gih = (const float*)d_in[3];
  const float* b_gih = (const float*)d_in[4];
  const float* W_glh = (const float*)d_in[5];
  const float* W_grh = (const float*)d_in[6];
  const float* W_cih = (const float*)d_in[7];
  const float* b_cih = (const float*)d_in[8];
  const float* W_clh = (const float*)d_in[9];
  const float* W_crh = (const float*)d_in[10];
  float* out = (float*)d_out;

  char* ws = (char*)d_ws;
  size_t cur = 0;
  auto alloc = [&](size_t bytes) -> char* {
    char* p = ws + cur;
    cur += (bytes + 255) & ~(size_t)255;
    return p;
  };

  // xb holds only internal x rows (0..16383) + pad for tail-block overreads
  unsigned short* xb = (unsigned short*)alloc((size_t)(16384 + 128) * 256 * 2);
  unsigned short* hb = (unsigned short*)alloc((size_t)1025 * 16384 * 2);
  unsigned short* Wg = (unsigned short*)alloc((size_t)1280 * 768 * 2);
  unsigned short* Wc = (unsigned short*)alloc((size_t)256 * 768 * 2);
  unsigned short* Wl = (unsigned short*)alloc((size_t)512 * 256 * 2);

  size_t rem = (ws_size > cur) ? (ws_size - cur) : 0;
  long long rcap = (long long)(rem / (7 * 512 + 64));
  rcap = (rcap / 128) * 128;
  int Rchunk = (int)((rcap < 11008) ? rcap : 11008);  // max internal level = 10944 rows
  if (Rchunk < 128) Rchunk = 128;

  unsigned short* lh  = (unsigned short*)alloc((size_t)Rchunk * 512);
  unsigned short* rh  = (unsigned short*)alloc((size_t)Rchunk * 512);
  unsigned short* a2l = (unsigned short*)alloc((size_t)Rchunk * 512);
  unsigned short* a2r = (unsigned short*)alloc((size_t)Rchunk * 512);
  unsigned short* p1  = (unsigned short*)alloc((size_t)Rchunk * 512);
  unsigned short* p2  = (unsigned short*)alloc((size_t)Rchunk * 512);
  unsigned short* zb  = (unsigned short*)alloc((size_t)Rchunk * 512);

  k_pre<<<5120, 256, 0, stream>>>(inputs, W_gih, W_glh, W_grh, W_cih, W_clh, W_crh,
                                  xb, Wg, Wc, Wl, hb);

  // leaves (nodes 256..1023): 49152 rows, N=512 interleaved, K=256, fp32-direct A
  k_leaf<<<1536, 512, 0, stream>>>(inputs + (size_t)16384 * 256, Wl, b_gih, b_cih, 1536, hb, out);

  // internal levels bottom-up
  static const int LSi[5] = {0, 1, 5, 21, 85};
  static const int LCi[5] = {1, 4, 16, 64, 171};

  for (int d = 4; d >= 0; --d) {
    int rows_lvl = LCi[d] * 64;
    for (int off = 0; off < rows_lvl; off += Rchunk) {
      int rows = rows_lvl - off;
      if (rows > Rchunk) rows = Rchunk;
      int tmn = (rows + 127) / 128;
      int pgrid = (rows * 32 + 255) / 256;
      k_prep<<<pgrid, 256, 0, stream>>>(hb, lh, rh, rows, off, LSi[d]);
      const unsigned short* xseg = xb + (size_t)(LSi[d] * 64 + off) * 256;
      int nwg_g = tmn * 10;
      if (nwg_g <= 256)
        k_gates_s<<<nwg_g, 512, 0, stream>>>(xseg, lh, rh, Wg, b_gih, rows, off, LSi[d], nwg_g,
                                             lh, rh, a2l, a2r, p1, p2, zb);
      else
        k_gates<<<nwg_g, 512, 0, stream>>>(xseg, lh, rh, Wg, b_gih, rows, off, LSi[d], nwg_g,
                                           lh, rh, a2l, a2r, p1, p2, zb);
      int nwg_c = tmn * 2;
      k_cell_s<<<nwg_c, 512, 0, stream>>>(xseg, a2l, a2r, Wc, b_cih, rows, off, LSi[d], nwg_c,
                                          p1, p2, zb, hb, out);
    }
  }
}